// Round 4
// baseline (439.960 us; speedup 1.0000x reference)
//
#include <hip/hip_runtime.h>
#include <math.h>

// ---------------------------------------------------------------------------
// Fastformer encoder layer — Round 4: flat-B fp16 MFMA GEMMs.
//
// R3 post-mortem: fp16x1 GEMMs are staging/VALU-bound (MfmaUtil 27%,
// VALUBusy 36%): wave 64x64 has 16 MFMA (78cyc) vs 8 ds_read_b128 (96cyc)
// per k32. R4 restructures:
//   * B (weights, L2-hot) loaded DIRECT global->fragment regs, reg-double-
//     buffered — no barrier dependency, fine-grained vmcnt overlap.
//   * Wave tile 128x64 (acc 128 regs): 32 MFMA vs 8 A-frag ds_reads per k32.
//   * Block 256 thr = 4 waves (2x2), block tile 256 rows x 128 cols,
//     A staged via global_load_lds (32KB, XOR-swizzled, 2-way max = free).
//   * kv GEMM outputs fp16 (halves attn/vscale traffic); attn split into
//     512-block partial pass + 128-block merge.
// ws (bytes): h16@0(16M) | kv16/act16@16M(32M, overlaid) | vq@48M(16M) |
//             weights@64M(18M) | gk@82M | attn partials@83M
// ---------------------------------------------------------------------------

#define DM     1024
#define FFH    2048
#define M_TOT  8192

typedef _Float16 f16x8 __attribute__((ext_vector_type(8)));
typedef float    f32x4 __attribute__((ext_vector_type(4)));

__device__ __forceinline__ void gl2lds16(const void* g, void* l) {
    __builtin_amdgcn_global_load_lds(
        (const __attribute__((address_space(1))) void*)g,
        (__attribute__((address_space(3))) void*)l, 16, 0, 0);
}
__device__ __forceinline__ unsigned short f2h(float x) {
    union { _Float16 h; unsigned short u; } c;
    c.h = (_Float16)x;
    return c.u;
}
__device__ __forceinline__ float h2f(unsigned short u) {
    union { unsigned short u; _Float16 h; } c;
    c.u = u;
    return (float)c.h;
}

// ---------------------------------------------------------------------------
// fused weight cast: all 4 weight matrices fp32 -> fp16 in one launch.
// ---------------------------------------------------------------------------
__global__ __launch_bounds__(256) void wcast_all(
    const float* __restrict__ s0, const float* __restrict__ s1,
    const float* __restrict__ s2, const float* __restrict__ s3,
    unsigned short* __restrict__ d0, unsigned short* __restrict__ d1,
    unsigned short* __restrict__ d2, unsigned short* __restrict__ d3)
{
    const int i = blockIdx.x * 256 + threadIdx.x;
    const float* s; unsigned short* d; int off;
    if      (i <  524288) { s = s0; d = d0; off = i; }
    else if (i <  786432) { s = s1; d = d1; off = i - 524288; }
    else if (i < 1835008) { s = s2; d = d2; off = i - 786432; }
    else                  { s = s3; d = d3; off = i - 1835008; }
    const float4 v = ((const float4*)s)[off];
    ushort4 h;
    h.x = f2h(v.x); h.y = f2h(v.y); h.z = f2h(v.z); h.w = f2h(v.w);
    ((ushort4*)d)[off] = h;
}

// ---------------------------------------------------------------------------
// LayerNorm -> fp16. One block/row, one float4/thread.
// ---------------------------------------------------------------------------
__global__ __launch_bounds__(256) void ln_f16(
    const float* __restrict__ x, const float* __restrict__ g,
    const float* __restrict__ b, unsigned short* __restrict__ y)
{
    const int row = blockIdx.x;
    const int t   = threadIdx.x;
    const float4 v = ((const float4*)(x + (size_t)row * DM))[t];

    float s  = v.x + v.y + v.z + v.w;
    float ss = v.x * v.x + v.y * v.y + v.z * v.z + v.w * v.w;
    #pragma unroll
    for (int off = 32; off > 0; off >>= 1) {
        s  += __shfl_xor(s, off);
        ss += __shfl_xor(ss, off);
    }
    __shared__ float sm[8];
    const int wave = t >> 6;
    if ((t & 63) == 0) { sm[wave * 2] = s; sm[wave * 2 + 1] = ss; }
    __syncthreads();
    s  = sm[0] + sm[2] + sm[4] + sm[6];
    ss = sm[1] + sm[3] + sm[5] + sm[7];

    const float mu  = s * (1.0f / DM);
    const float var = ss * (1.0f / DM) - mu * mu;
    const float r   = rsqrtf(var + 1e-5f);

    const float4 gv = ((const float4*)g)[t];
    const float4 bv = ((const float4*)b)[t];
    ushort4 o;
    o.x = f2h((v.x - mu) * r * gv.x + bv.x);
    o.y = f2h((v.y - mu) * r * gv.y + bv.y);
    o.z = f2h((v.z - mu) * r * gv.z + bv.z);
    o.w = f2h((v.w - mu) * r * gv.w + bv.w);
    ((ushort4*)(y + (size_t)row * DM))[t] = o;
}

// ---------------------------------------------------------------------------
// attention partial pass: 512 blocks = (b,h) x 4 n-quarters. Each wave owns
// 64 n's (online softmax over fp16 k), 4 waves merged in LDS; block writes
// one partial (m,l,s) per e.
// ---------------------------------------------------------------------------
__global__ __launch_bounds__(256) void attn_part(
    const unsigned short* __restrict__ kv, const float* __restrict__ kw,
    float* __restrict__ pm, float* __restrict__ pl, float* __restrict__ ps)
{
    const int blk = blockIdx.x;
    const int bh = blk >> 2, qt = blk & 3;
    const int b = bh >> 4, h = bh & 15;
    const int t = threadIdx.x, e = t & 63, w = t >> 6;
    const int nbase = qt * 256 + w * 64;
    const unsigned short* kp =
        kv + (size_t)b * 1024 * 2048 + (size_t)nbase * 2048 + h * 64 + e;
    const float* kwr = kw + h * 1024 + nbase;

    float m = -1e30f, l = 0.f, s = 0.f;
    #pragma unroll 4
    for (int i = 0; i < 64; ++i) {
        const float kval = h2f(kp[(size_t)i * 2048]);
        const float x    = kval * kwr[i] * 0.125f;
        const float nm   = fmaxf(m, x);
        const float c    = __expf(m - nm);
        const float ex   = __expf(x - nm);
        l = l * c + ex;
        s = s * c + ex * kval;
        m = nm;
    }
    __shared__ float sm[3][256];
    sm[0][t] = m; sm[1][t] = l; sm[2][t] = s;
    __syncthreads();
    if (t < 64) {
        #pragma unroll
        for (int ww = 1; ww < 4; ++ww) {
            const float m2 = sm[0][ww * 64 + e];
            const float l2 = sm[1][ww * 64 + e];
            const float s2 = sm[2][ww * 64 + e];
            const float nm = fmaxf(m, m2);
            const float c1 = __expf(m - nm);
            const float c2 = __expf(m2 - nm);
            l = l * c1 + l2 * c2;
            s = s * c1 + s2 * c2;
            m = nm;
        }
        const int o = blk * 64 + e;
        pm[o] = m; pl[o] = l; ps[o] = s;
    }
}

__global__ __launch_bounds__(64) void attn_merge(
    const float* __restrict__ pm, const float* __restrict__ pl,
    const float* __restrict__ ps, float* __restrict__ gk)
{
    const int bh = blockIdx.x, e = threadIdx.x;
    const int b = bh >> 4, h = bh & 15;
    int o = bh * 4 * 64 + e;
    float m = pm[o], l = pl[o], s = ps[o];
    #pragma unroll
    for (int qt = 1; qt < 4; ++qt) {
        o += 64;
        const float m2 = pm[o], l2 = pl[o], s2 = ps[o];
        const float nm = fmaxf(m, m2);
        const float c1 = __expf(m - nm);
        const float c2 = __expf(m2 - nm);
        l = l * c1 + l2 * c2;
        s = s * c1 + s2 * c2;
        m = nm;
    }
    gk[(size_t)b * DM + h * 64 + e] = s / l;
}

// ---------------------------------------------------------------------------
// v-scale: vq[m][d] = fp16( v16[m][d] * gk[batch][d] ).
// ---------------------------------------------------------------------------
__global__ __launch_bounds__(256) void vscale_f16(
    const unsigned short* __restrict__ kv, const float* __restrict__ gk,
    unsigned short* __restrict__ vq)
{
    const int m = blockIdx.x;
    const int t = threadIdx.x;
    const int b = m >> 10;
    const ushort4 v4 = *(const ushort4*)(kv + (size_t)m * 2048 + 1024 + t * 4);
    const float4  s4 = *(const float4*)(gk + b * DM + t * 4);
    ushort4 o;
    o.x = f2h(h2f(v4.x) * s4.x);
    o.y = f2h(h2f(v4.y) * s4.y);
    o.z = f2h(h2f(v4.z) * s4.z);
    o.w = f2h(h2f(v4.w) * s4.w);
    *(ushort4*)(vq + (size_t)m * DM + t * 4) = o;
}

// ---------------------------------------------------------------------------
// flat-B fp16 MFMA GEMM.  C[M,N] = A[M,K] @ W[N,K]^T + bias (+res).
// Block 256 thr (4 waves 2x2), tile 256 rows x 128 cols (LIN1ACT: 64 cols,
// wn=0 -> a-half, wn=1 -> g-half of W). Wave tile 128x64: 8 A-frags (LDS),
// 4 B-frags (direct global, reg-double-buffered). BK=64, 2 k32 stages.
// OUTM: 0 = fp16 out, 2 = fp32 out + residual.
// ---------------------------------------------------------------------------
template <bool LIN1ACT, int OUTM>
__global__ __launch_bounds__(256, 2) void fgemm(
    const unsigned short* __restrict__ A,
    const unsigned short* __restrict__ B,
    const float* __restrict__ bias,
    const float* __restrict__ residual,
    float* __restrict__ Cf, unsigned short* __restrict__ Cq,
    int K, int lda, int ldc)
{
    __shared__ __align__(16) char lds[36864];
    const int t  = threadIdx.x;
    const int m0 = blockIdx.y * 256;
    const int n0 = blockIdx.x * (LIN1ACT ? 64 : 128);
    const int L  = t & 63, w = t >> 6;
    const int wm = w >> 1, wn = w & 1;
    const int fr = L & 15, q = L >> 4;

    // A staging: 2048 16B-chunks, 8 per thread. chunk c=t+j*256,
    // row=c>>3 (0..255), chunk-in-row XOR-swizzled by row&7.
    const int arow = t >> 3;
    const int ach  = (t & 7) ^ (arow & 7);
    const unsigned short* pA0 = A + (size_t)(m0 + arow) * lda + ach * 8;
    char* ldsA0 = lds + t * 16;           // + j*4096

    // B fragment base: lane supplies W row (brow+ni*16), k octet q*8.
    const int brow = LIN1ACT ? ((wn ? FFH : 0) + n0 + fr)
                             : (n0 + wn * 64 + fr);
    const unsigned short* pB0 = B + (size_t)brow * K + q * 8;
    const size_t bstep = (size_t)16 * K;

    // A-frag LDS offsets (stage0; stage1 = ^64)
    int aoff[8];
    #pragma unroll
    for (int mi = 0; mi < 8; ++mi) {
        const int row = wm * 128 + mi * 16 + fr;
        aoff[mi] = row * 128 + ((q ^ (row & 7)) * 16);
    }

    f32x4 acc[8][4];
    #pragma unroll
    for (int i = 0; i < 8; ++i)
        #pragma unroll
        for (int j = 0; j < 4; ++j) acc[i][j] = (f32x4){0.f, 0.f, 0.f, 0.f};

    f16x8 bcur[4];
    #pragma unroll
    for (int ni = 0; ni < 4; ++ni)
        bcur[ni] = *(const f16x8*)(pB0 + ni * bstep);

    for (int k0 = 0; k0 < K; k0 += 64) {
        __syncthreads();
        #pragma unroll
        for (int j = 0; j < 8; ++j)
            gl2lds16(pA0 + (size_t)j * 32 * lda + k0, ldsA0 + j * 4096);
        f16x8 bnxt[4];
        #pragma unroll
        for (int ni = 0; ni < 4; ++ni)
            bnxt[ni] = *(const f16x8*)(pB0 + ni * bstep + k0 + 32);
        __syncthreads();

        f16x8 af[8];
        #pragma unroll
        for (int mi = 0; mi < 8; ++mi)
            af[mi] = *(const f16x8*)(lds + aoff[mi]);
        #pragma unroll
        for (int mi = 0; mi < 8; ++mi)
            #pragma unroll
            for (int ni = 0; ni < 4; ++ni)
                acc[mi][ni] = __builtin_amdgcn_mfma_f32_16x16x32_f16(
                    af[mi], bcur[ni], acc[mi][ni], 0, 0, 0);

        const int kn = (k0 + 64 < K) ? (k0 + 64) : 0;   // guard tail overread
        #pragma unroll
        for (int ni = 0; ni < 4; ++ni)
            bcur[ni] = *(const f16x8*)(pB0 + ni * bstep + kn);

        #pragma unroll
        for (int mi = 0; mi < 8; ++mi)
            af[mi] = *(const f16x8*)(lds + (aoff[mi] ^ 64));
        #pragma unroll
        for (int mi = 0; mi < 8; ++mi)
            #pragma unroll
            for (int ni = 0; ni < 4; ++ni)
                acc[mi][ni] = __builtin_amdgcn_mfma_f32_16x16x32_f16(
                    af[mi], bnxt[ni], acc[mi][ni], 0, 0, 0);
    }

    if (!LIN1ACT) {
        float bc[4];
        #pragma unroll
        for (int ni = 0; ni < 4; ++ni)
            bc[ni] = bias[n0 + wn * 64 + ni * 16 + fr];
        #pragma unroll
        for (int mi = 0; mi < 8; ++mi)
            #pragma unroll
            for (int ni = 0; ni < 4; ++ni) {
                const int gcol = n0 + wn * 64 + ni * 16 + fr;
                #pragma unroll
                for (int r = 0; r < 4; ++r) {
                    const int grow = m0 + wm * 128 + mi * 16 + q * 4 + r;
                    float v = acc[mi][ni][r] + bc[ni];
                    if (OUTM == 2) {
                        v += residual[(size_t)grow * ldc + gcol];
                        Cf[(size_t)grow * ldc + gcol] = v;
                    } else {
                        Cq[(size_t)grow * ldc + gcol] = f2h(v);
                    }
                }
            }
    } else {
        __syncthreads();                           // LDS: staging -> exchange
        unsigned short* xch = (unsigned short*)lds; // [256][72] fp16, padded
        if (wn == 1) {
            #pragma unroll
            for (int mi = 0; mi < 8; ++mi)
                #pragma unroll
                for (int ni = 0; ni < 4; ++ni) {
                    const int col = ni * 16 + fr;
                    const float bg = bias[FFH + n0 + col];
                    #pragma unroll
                    for (int r = 0; r < 4; ++r) {
                        const int row = wm * 128 + mi * 16 + q * 4 + r;
                        xch[row * 72 + col] =
                            f2h(fmaxf(acc[mi][ni][r] + bg, 0.f));
                    }
                }
        }
        __syncthreads();
        if (wn == 0) {
            #pragma unroll
            for (int mi = 0; mi < 8; ++mi)
                #pragma unroll
                for (int ni = 0; ni < 4; ++ni) {
                    const int col = ni * 16 + fr;
                    const float ba = bias[n0 + col];
                    #pragma unroll
                    for (int r = 0; r < 4; ++r) {
                        const int row = wm * 128 + mi * 16 + q * 4 + r;
                        const float a = acc[mi][ni][r] + ba;
                        const float o = a * h2f(xch[row * 72 + col]);
                        Cq[(size_t)(m0 + row) * FFH + n0 + col] = f2h(o);
                    }
                }
        }
    }
}

// ---------------------------------------------------------------------------
extern "C" void kernel_launch(void* const* d_in, const int* in_sizes, int n_in,
                              void* d_out, int out_size, void* d_ws, size_t ws_size,
                              hipStream_t stream)
{
    const float* hidden = (const float*)d_in[0];
    const float* qkv_w  = (const float*)d_in[2];
    const float* qkv_b  = (const float*)d_in[3];
    const float* out_w  = (const float*)d_in[4];
    const float* out_b  = (const float*)d_in[5];
    const float* key_w  = (const float*)d_in[7];
    const float* n1g    = (const float*)d_in[8];
    const float* n1b    = (const float*)d_in[9];
    const float* n2g    = (const float*)d_in[10];
    const float* n2b    = (const float*)d_in[11];
    const float* l1w    = (const float*)d_in[12];
    const float* l1b    = (const float*)d_in[13];
    const float* l2w    = (const float*)d_in[14];
    const float* l2b    = (const float*)d_in[15];
    float* out = (float*)d_out;
    char*  wsb = (char*)d_ws;

    const size_t MB = 1u << 20;
    unsigned short* h16   = (unsigned short*)wsb;               // 16 MB
    unsigned short* kv16  = (unsigned short*)(wsb + 16 * MB);   // 32 MB
    unsigned short* act16 = (unsigned short*)(wsb + 16 * MB);   // overlay
    unsigned short* vq    = (unsigned short*)(wsb + 48 * MB);   // 16 MB
    unsigned short* wkv16 = (unsigned short*)(wsb + 64 * MB);   // 4 MB
    unsigned short* wo16  = (unsigned short*)(wsb + 68 * MB);   // 2 MB
    unsigned short* wl116 = (unsigned short*)(wsb + 70 * MB);   // 8 MB
    unsigned short* wl216 = (unsigned short*)(wsb + 78 * MB);   // 4 MB
    float*          gk    = (float*)(wsb + 82 * MB);            // 32 KB
    float*          pm    = (float*)(wsb + 83 * MB);            // 128 KB
    float*          pl    = (float*)(wsb + 83 * MB + 131072);
    float*          ps    = (float*)(wsb + 83 * MB + 262144);

    // 0. weights fp32 -> fp16
    wcast_all<<<9216, 256, 0, stream>>>(
        qkv_w + (size_t)DM * DM, out_w, l1w, l2w,
        wkv16, wo16, wl116, wl216);

    // 1. h1 = LN1(hidden) -> fp16
    ln_f16<<<M_TOT, 256, 0, stream>>>(hidden, n1g, n1b, h16);

    // 2. kv16 = fp16( h1 @ Wkv^T + b )   (ldc 2048)
    fgemm<false, 0><<<dim3(16, 32), 256, 0, stream>>>(
        h16, wkv16, qkv_b + DM, nullptr, nullptr, kv16, 1024, 1024, 2048);

    // 3. global_key (partial + merge)
    attn_part<<<512, 256, 0, stream>>>(kv16, key_w, pm, pl, ps);
    attn_merge<<<128, 64, 0, stream>>>(pm, pl, ps, gk);

    // 4. vq = fp16(v * gk)
    vscale_f16<<<M_TOT, 256, 0, stream>>>(kv16, gk, vq);

    // 5. hidden2 = hidden + vq @ out_w^T + out_b  -> d_out
    fgemm<false, 2><<<dim3(8, 32), 256, 0, stream>>>(
        vq, wo16, out_b, hidden, out, nullptr, 1024, 1024, 1024);

    // 6. h2 = LN2(hidden2) -> fp16
    ln_f16<<<M_TOT, 256, 0, stream>>>(out, n2g, n2b, h16);

    // 7. act16 = fp16( (h2@W_a^T + b_a) * relu(h2@W_g^T + b_g) )
    fgemm<true, 0><<<dim3(32, 32), 256, 0, stream>>>(
        h16, wl116, l1b, nullptr, nullptr, act16, 1024, 1024, 0);

    // 8. out = hidden2 + act @ l2w^T + l2b   (in-place residual on d_out)
    fgemm<false, 2><<<dim3(8, 32), 256, 0, stream>>>(
        act16, wl216, l2b, out, out, nullptr, 2048, 2048, 1024);
}